// Round 2
// baseline (15173.044 us; speedup 1.0000x reference)
//
#include <hip/hip_runtime.h>
#include <math.h>

#define B_ROWS 131072
#define D_DIM  1024
#define E_EXP  64
#define BM     64                 // rows per block
#define DC     32                 // d-chunk
#define NC     (D_DIM / DC)       // 32 chunks
#define RPW    16                 // rows per wave

// ---------- helpers ----------

__device__ __forceinline__ float softplus_f(float t) {
  return (t > 20.0f) ? t : log1pf(expf(t));
}

__device__ __forceinline__ float ndtr_f(float z) {
  return 0.5f * erfcf(-z * 0.70710678118654752f);
}

// wave-wide argmax over 64 lanes, ties -> smaller lane index (matches jax top_k)
__device__ __forceinline__ void argmax64(float& v, int& vi) {
  #pragma unroll
  for (int off = 32; off > 0; off >>= 1) {
    float ov = __shfl_xor(v, off, 64);
    int   oi = __shfl_xor(vi, off, 64);
    if (ov > v || (ov == v && oi < vi)) { v = ov; vi = oi; }
  }
}

__device__ __forceinline__ float sum64(float v) {
  #pragma unroll
  for (int off = 32; off > 0; off >>= 1) v += __shfl_xor(v, off, 64);
  return v;
}

#define AS1C(p) ((const __attribute__((address_space(1))) void*)(p))
#define AS3(p)  ((__attribute__((address_space(3))) void*)(p))

// ---------- kernels ----------

__global__ void init_acc(float* load_o, float* imp_o, float* zsum) {
  int t = threadIdx.x;
  if (t < 64) { load_o[t] = 0.0f; imp_o[t] = 0.0f; }
  if (t == 64) zsum[0] = 0.0f;
}

__global__ __launch_bounds__(256, 3) void router_main(
    const float* __restrict__ x,       // [B, D]
    const float* __restrict__ wgm,     // [D, E]
    const float* __restrict__ wnm,     // [D, E]
    const float* __restrict__ eps,     // [B, E]
    float* __restrict__ out_gates,     // [B, E]
    float* __restrict__ out_load,      // [E]
    float* __restrict__ out_logits,    // [B, E]
    float* __restrict__ out_imp,       // [E]
    float* __restrict__ zsum)          // [1] in workspace
{
  __shared__ float xs[2][BM][DC];        // 16 KB
  __shared__ float wgs[2][DC][E_EXP];    // 16 KB
  __shared__ float wns[2][DC][E_EXP];    // 16 KB

  const int lane = threadIdx.x & 63;     // lane == expert index
  const int wid  = threadIdx.x >> 6;
  const int row0 = blockIdx.x * BM;
  const int wrow = wid * RPW;

  // async global->LDS staging. x: each wave issues 2x 1KB (its own 16 rows x 32 d).
  auto issue_x = [&](int dt, int buf) {
    #pragma unroll
    for (int i = 0; i < 2; ++i) {
      const float* gp = x + (size_t)(row0 + wrow + i * 8 + (lane >> 3)) * D_DIM
                          + dt + ((lane & 7) << 2);
      __builtin_amdgcn_global_load_lds(AS1C(gp), AS3(&xs[buf][wrow + i * 8][0]), 16, 0, 0);
    }
  };
  // w: each wave issues 2x 1KB per matrix (4 d-rows per issue), block covers all 32 d-rows.
  auto issue_w = [&](const float* wm, float* dst /* [DC][E_EXP] flat */, int dt) {
    #pragma unroll
    for (int i = 0; i < 2; ++i) {
      const int d4 = (wid * 2 + i) * 4;
      const float* gp = wm + (size_t)(dt + d4 + (lane >> 4)) * E_EXP + ((lane & 15) << 2);
      __builtin_amdgcn_global_load_lds(AS1C(gp), AS3(dst + d4 * E_EXP), 16, 0, 0);
    }
  };

  float accg[RPW], accn[RPW];
  #pragma unroll
  for (int r = 0; r < RPW; ++r) { accg[r] = 0.0f; accn[r] = 0.0f; }

  // prologue: stage chunk 0
  issue_x(0, 0);
  issue_w(wgm, &wgs[0][0][0], 0);
  issue_w(wnm, &wns[0][0][0], 0);
  asm volatile("s_waitcnt vmcnt(0)" ::: "memory");
  __syncthreads();

  for (int k = 0; k < NC; ++k) {
    const int cur = k & 1;
    const int dt  = k * DC;

    // prefetch chunk k+1 into the other buffer (async, drains at end-of-iter barrier)
    if (k + 1 < NC) {
      issue_x(dt + DC, cur ^ 1);
      issue_w(wgm, &wgs[cur ^ 1][0][0], dt + DC);
      issue_w(wnm, &wns[cur ^ 1][0][0], dt + DC);
    }

    // stage w chunk into registers (2-way bank aliasing = free)
    float wgv[DC], wnv[DC];
    #pragma unroll
    for (int j = 0; j < DC; ++j) {
      wgv[j] = wgs[cur][j][lane];
      wnv[j] = wns[cur][j][lane];
    }

    // FMA core: 16 rows x 32 d x 2 matrices
    #pragma unroll
    for (int r = 0; r < RPW; ++r) {
      const float4* xp = (const float4*)&xs[cur][wrow + r][0];
      #pragma unroll
      for (int q = 0; q < DC / 4; ++q) {
        float4 t = xp[q];                 // wave-uniform LDS broadcast
        accg[r] = fmaf(t.x, wgv[4*q+0], accg[r]);
        accn[r] = fmaf(t.x, wnv[4*q+0], accn[r]);
        accg[r] = fmaf(t.y, wgv[4*q+1], accg[r]);
        accn[r] = fmaf(t.y, wnv[4*q+1], accn[r]);
        accg[r] = fmaf(t.z, wgv[4*q+2], accg[r]);
        accn[r] = fmaf(t.z, wnv[4*q+2], accn[r]);
        accg[r] = fmaf(t.w, wgv[4*q+3], accg[r]);
        accn[r] = fmaf(t.w, wnv[4*q+3], accn[r]);
      }
    }

    if (k + 1 < NC) {
      asm volatile("s_waitcnt vmcnt(0)" ::: "memory");
      __syncthreads();
    }
  }

  // ---- epilogue: per-row noisy top-k routing ----
  float load_acc = 0.0f, imp_acc = 0.0f, z_acc = 0.0f;

  #pragma unroll
  for (int r = 0; r < RPW; ++r) {
    const int row = row0 + wrow + r;
    const float clean  = accg[r];
    const float stddev = softplus_f(accn[r]) + 0.01f;
    const float ev     = eps[(size_t)row * E_EXP + lane];
    const float l      = fmaf(ev, stddev, clean);   // noisy logit for expert `lane`

    // top-3 of 64 lanes
    float v1 = l; int i1 = lane;
    argmax64(v1, i1);
    float v2 = (lane == i1) ? -INFINITY : l; int i2 = lane;
    argmax64(v2, i2);
    float v3 = (lane == i1 || lane == i2) ? -INFINITY : l; int i3 = lane;
    argmax64(v3, i3);
    (void)i3;

    // softmax over [v1, v2]
    const float e21 = expf(v2 - v1);
    const float g1  = 1.0f / (1.0f + e21);
    const float g2  = e21 * g1;
    const float gv  = (lane == i1) ? g1 : ((lane == i2) ? g2 : 0.0f);

    out_gates [(size_t)row * E_EXP + lane] = gv;
    out_logits[(size_t)row * E_EXP + lane] = l;

    // z-loss: logsumexp over experts (v1 is the max)
    const float ssum = sum64(expf(l - v1));
    z_acc += v1 + logf(ssum);

    // load: where(l > v3, ndtr((clean-v3)/sd), ndtr((clean-v2)/sd))
    const bool  isin = l > v3;
    const float thr  = isin ? v3 : v2;
    load_acc += ndtr_f((clean - thr) / stddev);
    imp_acc  += gv;
  }

  atomicAdd(&out_load[lane], load_acc);
  atomicAdd(&out_imp[lane],  imp_acc);
  if (lane == 0) atomicAdd(zsum, z_acc);
}

__global__ void finalize_k(const float* __restrict__ load_o,
                           const float* __restrict__ imp_o,
                           const float* __restrict__ zsum,
                           float* __restrict__ out_lb) {
  if (threadIdx.x == 0 && blockIdx.x == 0) {
    double sl = 0.0, sl2 = 0.0, si = 0.0, si2 = 0.0;
    for (int e = 0; e < E_EXP; ++e) {
      double a = (double)load_o[e]; sl += a; sl2 += a * a;
      double b = (double)imp_o[e];  si += b; si2 += b * b;
    }
    const double n  = (double)E_EXP;
    const double ml = sl / n, mi = si / n;
    const double varl = (sl2 - n * ml * ml) / (n - 1.0);
    const double vari = (si2 - n * mi * mi) / (n - 1.0);
    const double cvl = varl / (ml * ml + 1e-10);
    const double cvi = vari / (mi * mi + 1e-10);
    const double z  = (double)zsum[0] / (double)B_ROWS;
    out_lb[0] = (float)(cvi + cvl + z);
  }
}

// ---------- launch ----------

extern "C" void kernel_launch(void* const* d_in, const int* in_sizes, int n_in,
                              void* d_out, int out_size, void* d_ws, size_t ws_size,
                              hipStream_t stream) {
  const float* x   = (const float*)d_in[0];
  const float* wg  = (const float*)d_in[1];
  const float* wn  = (const float*)d_in[2];
  const float* eps = (const float*)d_in[3];

  float* out    = (float*)d_out;
  float* gates  = out;                                       // [B*E]
  float* load_o = out + (size_t)B_ROWS * E_EXP;              // [E]
  float* logits = load_o + E_EXP;                            // [B*E]
  float* lb     = logits + (size_t)B_ROWS * E_EXP;           // [1]
  float* imp    = lb + 1;                                    // [E]
  float* zsum   = (float*)d_ws;                              // [1]

  init_acc<<<1, 128, 0, stream>>>(load_o, imp, zsum);
  router_main<<<B_ROWS / BM, 256, 0, stream>>>(
      x, wg, wn, eps, gates, load_o, logits, imp, zsum);
  finalize_k<<<1, 64, 0, stream>>>(load_o, imp, zsum, lb);
}

// Round 3
// 788.257 us; speedup vs baseline: 19.2488x; 19.2488x over previous
//
#include <hip/hip_runtime.h>
#include <math.h>

#define B_ROWS 131072
#define D_DIM  1024
#define E_EXP  64
#define BM     64                 // rows per block
#define DC     32                 // d-chunk
#define NC     (D_DIM / DC)       // 32 chunks
#define RPW    16                 // rows per wave

#define AS1C(p) ((const __attribute__((address_space(1))) void*)(p))
#define AS3(p)  ((__attribute__((address_space(3))) void*)(p))

// ---------- helpers ----------

__device__ __forceinline__ float softplus_f(float t) {
  return (t > 20.0f) ? t : log1pf(expf(t));
}

__device__ __forceinline__ float ndtr_f(float z) {
  return 0.5f * erfcf(-z * 0.70710678118654752f);
}

// wave-wide argmax over 64 lanes, ties -> smaller lane index (matches jax top_k)
__device__ __forceinline__ void argmax64(float& v, int& vi) {
  #pragma unroll
  for (int off = 32; off > 0; off >>= 1) {
    float ov = __shfl_xor(v, off, 64);
    int   oi = __shfl_xor(vi, off, 64);
    if (ov > v || (ov == v && oi < vi)) { v = ov; vi = oi; }
  }
}

__device__ __forceinline__ float sum64(float v) {
  #pragma unroll
  for (int off = 32; off > 0; off >>= 1) v += __shfl_xor(v, off, 64);
  return v;
}

// ---------- kernels ----------

__global__ void init_acc(float* load_o, float* imp_o, float* zsum) {
  int t = threadIdx.x;
  if (t < 64) { load_o[t] = 0.0f; imp_o[t] = 0.0f; }
  if (t == 64) zsum[0] = 0.0f;
}

__global__ __launch_bounds__(256, 3) void router_main(
    const float* __restrict__ x,       // [B, D]
    const float* __restrict__ wgm,     // [D, E]
    const float* __restrict__ wnm,     // [D, E]
    const float* __restrict__ eps,     // [B, E]
    float* __restrict__ out_gates,     // [B, E]
    float* __restrict__ out_load,      // [E]
    float* __restrict__ out_logits,    // [B, E]
    float* __restrict__ out_imp,       // [E]
    float* __restrict__ zsum)          // [1] in workspace
{
  __shared__ float xs[2][BM][DC];        // 16 KB
  __shared__ float wgs[2][DC][E_EXP];    // 16 KB
  __shared__ float wns[2][DC][E_EXP];    // 16 KB

  const int lane = threadIdx.x & 63;     // lane == expert index
  const int wid  = threadIdx.x >> 6;
  const int row0 = blockIdx.x * BM;
  const int wrow = wid * RPW;

  // Per-lane invariant global base pointers for async staging.
  // x: wave stages its own 16 rows as 2x 1KB issues (8 rows each);
  //    lane l covers row (l>>3), cols (l&7)*4 within the issue.
  const float* xg0 = x + (size_t)(row0 + wrow + (lane >> 3)) * D_DIM + ((lane & 7) << 2);
  const float* xg1 = x + (size_t)(row0 + wrow + 8 + (lane >> 3)) * D_DIM + ((lane & 7) << 2);
  // w: block stages [DC][64] per matrix as 8x 1KB issues, 2 per wave per matrix;
  //    issue covers 4 d-rows; lane l covers d-row (l>>4), cols (l&15)*4.
  const int wd0 = (wid * 2 + 0) * 4;
  const int wd1 = (wid * 2 + 1) * 4;
  const size_t woff0 = (size_t)(wd0 + (lane >> 4)) * E_EXP + ((lane & 15) << 2);
  const size_t woff1 = (size_t)(wd1 + (lane >> 4)) * E_EXP + ((lane & 15) << 2);
  const float* wgp0 = wgm + woff0;
  const float* wgp1 = wgm + woff1;
  const float* wnp0 = wnm + woff0;
  const float* wnp1 = wnm + woff1;

#define STAGE(buf, dt) do {                                                                        \
    __builtin_amdgcn_global_load_lds(AS1C(xg0 + (dt)),                AS3(&xs[buf][wrow][0]),     16, 0, 0); \
    __builtin_amdgcn_global_load_lds(AS1C(xg1 + (dt)),                AS3(&xs[buf][wrow + 8][0]), 16, 0, 0); \
    __builtin_amdgcn_global_load_lds(AS1C(wgp0 + (size_t)(dt) * E_EXP), AS3(&wgs[buf][wd0][0]),   16, 0, 0); \
    __builtin_amdgcn_global_load_lds(AS1C(wgp1 + (size_t)(dt) * E_EXP), AS3(&wgs[buf][wd1][0]),   16, 0, 0); \
    __builtin_amdgcn_global_load_lds(AS1C(wnp0 + (size_t)(dt) * E_EXP), AS3(&wns[buf][wd0][0]),   16, 0, 0); \
    __builtin_amdgcn_global_load_lds(AS1C(wnp1 + (size_t)(dt) * E_EXP), AS3(&wns[buf][wd1][0]),   16, 0, 0); \
  } while (0)

  float accg[RPW], accn[RPW];
  #pragma unroll
  for (int r = 0; r < RPW; ++r) { accg[r] = 0.0f; accn[r] = 0.0f; }

  // prologue: stage chunk 0 (syncthreads drains vmcnt before barrier)
  STAGE(0, 0);
  __syncthreads();

  for (int k = 0; k < NC; ++k) {
    const int cur = k & 1;

    // async prefetch of chunk k+1 into the other buffer; overlaps the FMAs below
    if (k + 1 < NC) STAGE(cur ^ 1, (k + 1) * DC);

    #pragma unroll
    for (int jt = 0; jt < DC / 8; ++jt) {
      const int j0 = jt * 8;
      // stage 8 d-values of w into named scalars (2-way bank alias = free)
      const float wgr0 = wgs[cur][j0 + 0][lane], wgr1 = wgs[cur][j0 + 1][lane];
      const float wgr2 = wgs[cur][j0 + 2][lane], wgr3 = wgs[cur][j0 + 3][lane];
      const float wgr4 = wgs[cur][j0 + 4][lane], wgr5 = wgs[cur][j0 + 5][lane];
      const float wgr6 = wgs[cur][j0 + 6][lane], wgr7 = wgs[cur][j0 + 7][lane];
      const float wnr0 = wns[cur][j0 + 0][lane], wnr1 = wns[cur][j0 + 1][lane];
      const float wnr2 = wns[cur][j0 + 2][lane], wnr3 = wns[cur][j0 + 3][lane];
      const float wnr4 = wns[cur][j0 + 4][lane], wnr5 = wns[cur][j0 + 5][lane];
      const float wnr6 = wns[cur][j0 + 6][lane], wnr7 = wns[cur][j0 + 7][lane];

      #pragma unroll
      for (int r = 0; r < RPW; ++r) {
        const float4* xp = reinterpret_cast<const float4*>(&xs[cur][wrow + r][j0]);
        const float4 xa = xp[0];            // wave-uniform LDS broadcast
        const float4 xb = xp[1];
        accg[r] = fmaf(xa.x, wgr0, accg[r]);  accn[r] = fmaf(xa.x, wnr0, accn[r]);
        accg[r] = fmaf(xa.y, wgr1, accg[r]);  accn[r] = fmaf(xa.y, wnr1, accn[r]);
        accg[r] = fmaf(xa.z, wgr2, accg[r]);  accn[r] = fmaf(xa.z, wnr2, accn[r]);
        accg[r] = fmaf(xa.w, wgr3, accg[r]);  accn[r] = fmaf(xa.w, wnr3, accn[r]);
        accg[r] = fmaf(xb.x, wgr4, accg[r]);  accn[r] = fmaf(xb.x, wnr4, accn[r]);
        accg[r] = fmaf(xb.y, wgr5, accg[r]);  accn[r] = fmaf(xb.y, wnr5, accn[r]);
        accg[r] = fmaf(xb.z, wgr6, accg[r]);  accn[r] = fmaf(xb.z, wnr6, accn[r]);
        accg[r] = fmaf(xb.w, wgr7, accg[r]);  accn[r] = fmaf(xb.w, wnr7, accn[r]);
      }
    }

    // barrier (with implicit vmcnt(0) drain) publishes chunk k+1 and retires chunk k
    __syncthreads();
  }
#undef STAGE

  // ---- epilogue: per-row noisy top-k routing ----
  float load_acc = 0.0f, imp_acc = 0.0f, z_acc = 0.0f;

  #pragma unroll
  for (int r = 0; r < RPW; ++r) {
    const int row = row0 + wrow + r;
    const float clean  = accg[r];
    const float stddev = softplus_f(accn[r]) + 0.01f;
    const float ev     = eps[(size_t)row * E_EXP + lane];
    const float l      = fmaf(ev, stddev, clean);   // noisy logit for expert `lane`

    // top-3 of 64 lanes
    float v1 = l; int i1 = lane;
    argmax64(v1, i1);
    float v2 = (lane == i1) ? -INFINITY : l; int i2 = lane;
    argmax64(v2, i2);
    float v3 = (lane == i1 || lane == i2) ? -INFINITY : l; int i3 = lane;
    argmax64(v3, i3);
    (void)i3;

    // softmax over [v1, v2]
    const float e21 = expf(v2 - v1);
    const float g1  = 1.0f / (1.0f + e21);
    const float g2  = e21 * g1;
    const float gv  = (lane == i1) ? g1 : ((lane == i2) ? g2 : 0.0f);

    out_gates [(size_t)row * E_EXP + lane] = gv;
    out_logits[(size_t)row * E_EXP + lane] = l;

    // z-loss: logsumexp over experts (v1 is the max)
    const float ssum = sum64(expf(l - v1));
    z_acc += v1 + logf(ssum);

    // load: where(l > v3, ndtr((clean-v3)/sd), ndtr((clean-v2)/sd))
    const bool  isin = l > v3;
    const float thr  = isin ? v3 : v2;
    load_acc += ndtr_f((clean - thr) / stddev);
    imp_acc  += gv;
  }

  atomicAdd(&out_load[lane], load_acc);
  atomicAdd(&out_imp[lane],  imp_acc);
  if (lane == 0) atomicAdd(zsum, z_acc);
}

__global__ void finalize_k(const float* __restrict__ load_o,
                           const float* __restrict__ imp_o,
                           const float* __restrict__ zsum,
                           float* __restrict__ out_lb) {
  if (threadIdx.x == 0 && blockIdx.x == 0) {
    double sl = 0.0, sl2 = 0.0, si = 0.0, si2 = 0.0;
    for (int e = 0; e < E_EXP; ++e) {
      double a = (double)load_o[e]; sl += a; sl2 += a * a;
      double b = (double)imp_o[e];  si += b; si2 += b * b;
    }
    const double n  = (double)E_EXP;
    const double ml = sl / n, mi = si / n;
    const double varl = (sl2 - n * ml * ml) / (n - 1.0);
    const double vari = (si2 - n * mi * mi) / (n - 1.0);
    const double cvl = varl / (ml * ml + 1e-10);
    const double cvi = vari / (mi * mi + 1e-10);
    const double z  = (double)zsum[0] / (double)B_ROWS;
    out_lb[0] = (float)(cvi + cvl + z);
  }
}

// ---------- launch ----------

extern "C" void kernel_launch(void* const* d_in, const int* in_sizes, int n_in,
                              void* d_out, int out_size, void* d_ws, size_t ws_size,
                              hipStream_t stream) {
  const float* x   = (const float*)d_in[0];
  const float* wg  = (const float*)d_in[1];
  const float* wn  = (const float*)d_in[2];
  const float* eps = (const float*)d_in[3];

  float* out    = (float*)d_out;
  float* gates  = out;                                       // [B*E]
  float* load_o = out + (size_t)B_ROWS * E_EXP;              // [E]
  float* logits = load_o + E_EXP;                            // [B*E]
  float* lb     = logits + (size_t)B_ROWS * E_EXP;           // [1]
  float* imp    = lb + 1;                                    // [E]
  float* zsum   = (float*)d_ws;                              // [1]

  init_acc<<<1, 128, 0, stream>>>(load_o, imp, zsum);
  router_main<<<B_ROWS / BM, 256, 0, stream>>>(
      x, wg, wn, eps, gates, load_o, logits, imp, zsum);
  finalize_k<<<1, 64, 0, stream>>>(load_o, imp, zsum, lb);
}

// Round 4
// 486.656 us; speedup vs baseline: 31.1782x; 1.6197x over previous
//
#include <hip/hip_runtime.h>
#include <math.h>

#define B_ROWS 131072
#define D_DIM  1024
#define E_EXP  64
#define MARGIN 2e-3f
#define FLAGCAP 32768

typedef _Float16 f16;
typedef _Float16 f16x8 __attribute__((ext_vector_type(8)));
typedef float    f32x4 __attribute__((ext_vector_type(4)));

// ---------- helpers ----------

__device__ __forceinline__ float softplus_f(float t) {
  return (t > 20.0f) ? t : log1pf(expf(t));
}
__device__ __forceinline__ float ndtr_f(float z) {
  return 0.5f * erfcf(-z * 0.70710678118654752f);
}
__device__ __forceinline__ void argmax64(float& v, int& vi) {
  #pragma unroll
  for (int off = 32; off > 0; off >>= 1) {
    float ov = __shfl_xor(v, off, 64);
    int   oi = __shfl_xor(vi, off, 64);
    if (ov > v || (ov == v && oi < vi)) { v = ov; vi = oi; }
  }
}
__device__ __forceinline__ float sum64(float v) {
  #pragma unroll
  for (int off = 32; off > 0; off >>= 1) v += __shfl_xor(v, off, 64);
  return v;
}

// shared row epilogue: top-3, gates, logits, load/imp/z. Returns false if
// the v2-v3 gap is below `margin` (caller flags the row for fp32 fixup).
__device__ __forceinline__ bool row_epilogue(
    int row, int lane, float clean, float sd, float l, float margin,
    float* __restrict__ gates_buf, float* __restrict__ logits_buf,
    float& load_acc, float& imp_acc, float& z_acc)
{
  float v1 = l; int i1 = lane; argmax64(v1, i1);
  float v2 = (lane == i1) ? -INFINITY : l; int i2 = lane; argmax64(v2, i2);
  float v3 = (lane == i1 || lane == i2) ? -INFINITY : l; int i3 = lane; argmax64(v3, i3);
  (void)i3;
  if (v2 - v3 < margin) return false;

  const float e21 = expf(v2 - v1);
  const float g1  = 1.0f / (1.0f + e21);
  const float g2  = e21 * g1;
  const float gv  = (lane == i1) ? g1 : ((lane == i2) ? g2 : 0.0f);

  gates_buf [(size_t)row * E_EXP + lane] = gv;
  logits_buf[(size_t)row * E_EXP + lane] = l;

  const float ssum = sum64(expf(l - v1));
  z_acc += v1 + logf(ssum);
  const bool  isin = l > v3;
  const float thr  = isin ? v3 : v2;
  load_acc += ndtr_f((clean - thr) / sd);
  imp_acc  += gv;
  return true;
}

// ---------- kernels ----------

__global__ void init_acc(float* load_o, float* imp_o, float* zsum, int* flagcnt) {
  int t = threadIdx.x;
  if (t < 64) { load_o[t] = 0.0f; imp_o[t] = 0.0f; }
  if (t == 64) zsum[0] = 0.0f;
  if (t == 65) flagcnt[0] = 0;
}

// W^T f16: wt[col][k], col 0..63 = w_gate experts, 64..127 = w_noise experts
__global__ __launch_bounds__(256) void prep_wt(
    const float* __restrict__ wg, const float* __restrict__ wn, f16* __restrict__ wt) {
  int idx = blockIdx.x * 256 + threadIdx.x;       // 0..131071
  int col = idx >> 10, k = idx & 1023;
  float v = (col < 64) ? wg[(size_t)k * 64 + col] : wn[(size_t)k * 64 + (col - 64)];
  wt[(size_t)col * 1024 + k] = (f16)v;
}

// MFMA GEMM: clean -> logits slot, sdraw -> gates slot (both fp32).
// Block: 4 waves x 32 rows = 128 rows. Wave: 32 rows x 128 cols.
__global__ __launch_bounds__(256, 2) void gemm_mfma(
    const float* __restrict__ x, const f16* __restrict__ wt,
    float* __restrict__ clean_buf, float* __restrict__ sdraw_buf)
{
  __shared__ __align__(16) char wlds[2][16384];   // [buf][128 cols x 64 k x f16], XOR-swizzled

  const int tid  = threadIdx.x;
  const int lane = tid & 63;
  const int wid  = tid >> 6;
  const int l15  = lane & 15;
  const int l4   = lane >> 4;
  const size_t rowbase = (size_t)blockIdx.x * 128 + wid * 32;

  // B staging: thread covers col = tid>>1, half = tid&1 (64B = 4x16B pieces)
  const int scol  = tid >> 1, shalf = tid & 1;
  const char* wsrc = (const char*)wt + (size_t)scol * 2048 + shalf * 64;
  const int sb = scol * 128 + shalf * 64;
  const int sx = (scol & 7) << 4;
  const int so0 = (sb +  0) ^ sx, so1 = (sb + 16) ^ sx;
  const int so2 = (sb + 32) ^ sx, so3 = (sb + 48) ^ sx;

  // A: lane reads x[row(rt)][k0 + 8*l4 .. +7] fp32 (two float4)
  const float* xp0 = x + (rowbase +  0 + l15) * D_DIM + l4 * 8;
  const float* xp1 = x + (rowbase + 16 + l15) * D_DIM + l4 * 8;

  f32x4 acc[2][8];
  #pragma unroll
  for (int rt = 0; rt < 2; ++rt)
    #pragma unroll
    for (int et = 0; et < 8; ++et) acc[rt][et] = (f32x4)0.0f;

  // prologue: stage chunk 0
  float4 w0 = *(const float4*)(wsrc +  0);
  float4 w1 = *(const float4*)(wsrc + 16);
  float4 w2 = *(const float4*)(wsrc + 32);
  float4 w3 = *(const float4*)(wsrc + 48);
  *(float4*)(&wlds[0][so0]) = w0;
  *(float4*)(&wlds[0][so1]) = w1;
  *(float4*)(&wlds[0][so2]) = w2;
  *(float4*)(&wlds[0][so3]) = w3;
  __syncthreads();

  #pragma unroll 1
  for (int kc = 0; kc < 16; ++kc) {
    const int buf = kc & 1;
    const int ko  = kc * 64;            // k offset (floats) of this chunk

    // A loads for both ksteps of this chunk (HBM-critical, issue first)
    float4 xa[2][2][2];                 // [kl][rt][half16B]
    #pragma unroll
    for (int kl = 0; kl < 2; ++kl) {
      xa[kl][0][0] = *(const float4*)(xp0 + ko + kl * 32 + 0);
      xa[kl][0][1] = *(const float4*)(xp0 + ko + kl * 32 + 4);
      xa[kl][1][0] = *(const float4*)(xp1 + ko + kl * 32 + 0);
      xa[kl][1][1] = *(const float4*)(xp1 + ko + kl * 32 + 4);
    }
    // B prefetch (next chunk) into regs
    if (kc < 15) {
      const char* ws = wsrc + (kc + 1) * 128;
      w0 = *(const float4*)(ws +  0);
      w1 = *(const float4*)(ws + 16);
      w2 = *(const float4*)(ws + 32);
      w3 = *(const float4*)(ws + 48);
    }

    // split A into f16 hi/lo frags
    f16x8 ah[2][2], al[2][2];
    #pragma unroll
    for (int kl = 0; kl < 2; ++kl)
      #pragma unroll
      for (int rt = 0; rt < 2; ++rt) {
        #pragma unroll
        for (int h = 0; h < 2; ++h) {
          const float4 v = xa[kl][rt][h];
          #pragma unroll
          for (int j = 0; j < 4; ++j) {
            const float f = (j == 0) ? v.x : (j == 1) ? v.y : (j == 2) ? v.z : v.w;
            const f16 hi = (f16)f;
            ah[kl][rt][h * 4 + j] = hi;
            al[kl][rt][h * 4 + j] = (f16)(f - (float)hi);
          }
        }
      }

    // MFMA: 2 ksteps x 8 e-tiles x 2 row-tiles x (hi+lo)
    #pragma unroll
    for (int kl = 0; kl < 2; ++kl) {
      #pragma unroll
      for (int et = 0; et < 8; ++et) {
        const int bcol = et * 16 + l15;
        const int boff = (bcol * 128 + kl * 64 + l4 * 16) ^ ((bcol & 7) << 4);
        const f16x8 b = *(const f16x8*)(&wlds[buf][boff]);
        #pragma unroll
        for (int rt = 0; rt < 2; ++rt) {
          acc[rt][et] = __builtin_amdgcn_mfma_f32_16x16x32_f16(ah[kl][rt], b, acc[rt][et], 0, 0, 0);
          acc[rt][et] = __builtin_amdgcn_mfma_f32_16x16x32_f16(al[kl][rt], b, acc[rt][et], 0, 0, 0);
        }
      }
    }

    // publish next chunk
    if (kc < 15) {
      *(float4*)(&wlds[buf ^ 1][so0]) = w0;
      *(float4*)(&wlds[buf ^ 1][so1]) = w1;
      *(float4*)(&wlds[buf ^ 1][so2]) = w2;
      *(float4*)(&wlds[buf ^ 1][so3]) = w3;
    }
    __syncthreads();
  }

  // store: C[row][col], row = rowbase + rt*16 + l4*4 + reg, col = et*16+l15
  #pragma unroll
  for (int rt = 0; rt < 2; ++rt)
    #pragma unroll
    for (int et = 0; et < 8; ++et) {
      float* dst = (et < 4) ? clean_buf : sdraw_buf;
      const int e = (et & 3) * 16 + l15;
      #pragma unroll
      for (int reg = 0; reg < 4; ++reg) {
        const size_t row = rowbase + rt * 16 + l4 * 4 + reg;
        dst[row * E_EXP + e] = acc[rt][et][reg];
      }
    }
}

// epilogue: reads clean (logits slot) + sdraw (gates slot), overwrites in place.
__global__ __launch_bounds__(256) void epilogue_k(
    const float* __restrict__ eps,
    float* __restrict__ gates_buf, float* __restrict__ logits_buf,
    float* __restrict__ load_o, float* __restrict__ imp_o, float* __restrict__ zsum,
    int* __restrict__ flagcnt, int* __restrict__ flaglist)
{
  const int lane = threadIdx.x & 63;
  const int wid  = threadIdx.x >> 6;
  const int row0 = (blockIdx.x * 4 + wid) * 16;

  float load_acc = 0.0f, imp_acc = 0.0f, z_acc = 0.0f;

  for (int r = 0; r < 16; ++r) {
    const int row = row0 + r;
    const float clean = logits_buf[(size_t)row * E_EXP + lane];
    const float sdraw = gates_buf [(size_t)row * E_EXP + lane];
    const float sd    = softplus_f(sdraw) + 0.01f;
    const float ev    = eps[(size_t)row * E_EXP + lane];
    const float l     = fmaf(ev, sd, clean);

    if (!row_epilogue(row, lane, clean, sd, l, MARGIN,
                      gates_buf, logits_buf, load_acc, imp_acc, z_acc)) {
      // ambiguous row -> flag for fp32 fixup
      int spill = 0;
      if (lane == 0) {
        int idx = atomicAdd(flagcnt, 1);
        if (idx < FLAGCAP) flaglist[idx] = row; else spill = 1;
      }
      spill = __shfl(spill, 0, 64);
      if (spill) {  // capacity overflow (practically impossible): process inline
        row_epilogue(row, lane, clean, sd, l, -1e30f,
                     gates_buf, logits_buf, load_acc, imp_acc, z_acc);
      }
    }
  }

  atomicAdd(&load_o[lane], load_acc);
  atomicAdd(&imp_o[lane],  imp_acc);
  if (lane == 0) atomicAdd(zsum, z_acc);
}

// exact fp32 recompute of flagged rows
__global__ __launch_bounds__(256) void fixup_k(
    const float* __restrict__ x, const float* __restrict__ wg, const float* __restrict__ wn,
    const float* __restrict__ eps,
    float* __restrict__ gates_buf, float* __restrict__ logits_buf,
    float* __restrict__ load_o, float* __restrict__ imp_o, float* __restrict__ zsum,
    const int* __restrict__ flagcnt, const int* __restrict__ flaglist)
{
  const int lane = threadIdx.x & 63;
  const int wid  = threadIdx.x >> 6;
  __shared__ float redg[4][64], redn[4][64];

  int nf = *flagcnt;
  if (nf > FLAGCAP) nf = FLAGCAP;

  for (int it = blockIdx.x; it < nf; it += gridDim.x) {
    const int row = flaglist[it];
    float dg = 0.0f, dn = 0.0f;
    const float* xr = x + (size_t)row * D_DIM + wid * 256;
    for (int d = 0; d < 256; d += 4) {
      const float4 xv = *(const float4*)(xr + d);
      const int db = (wid * 256 + d) * E_EXP + lane;
      dg = fmaf(xv.x, wg[db +   0], dg);  dn = fmaf(xv.x, wn[db +   0], dn);
      dg = fmaf(xv.y, wg[db +  64], dg);  dn = fmaf(xv.y, wn[db +  64], dn);
      dg = fmaf(xv.z, wg[db + 128], dg);  dn = fmaf(xv.z, wn[db + 128], dn);
      dg = fmaf(xv.w, wg[db + 192], dg);  dn = fmaf(xv.w, wn[db + 192], dn);
    }
    redg[wid][lane] = dg; redn[wid][lane] = dn;
    __syncthreads();
    if (wid == 0) {
      const float clean = redg[0][lane] + redg[1][lane] + redg[2][lane] + redg[3][lane];
      const float sdraw = redn[0][lane] + redn[1][lane] + redn[2][lane] + redn[3][lane];
      const float sd    = softplus_f(sdraw) + 0.01f;
      const float ev    = eps[(size_t)row * E_EXP + lane];
      const float l     = fmaf(ev, sd, clean);
      float load_acc = 0.0f, imp_acc = 0.0f, z_acc = 0.0f;
      row_epilogue(row, lane, clean, sd, l, -1e30f,
                   gates_buf, logits_buf, load_acc, imp_acc, z_acc);
      atomicAdd(&load_o[lane], load_acc);
      atomicAdd(&imp_o[lane],  imp_acc);
      if (lane == 0) atomicAdd(zsum, z_acc);
    }
    __syncthreads();
  }
}

__global__ void finalize_k(const float* __restrict__ load_o,
                           const float* __restrict__ imp_o,
                           const float* __restrict__ zsum,
                           float* __restrict__ out_lb) {
  if (threadIdx.x == 0 && blockIdx.x == 0) {
    double sl = 0.0, sl2 = 0.0, si = 0.0, si2 = 0.0;
    for (int e = 0; e < E_EXP; ++e) {
      double a = (double)load_o[e]; sl += a; sl2 += a * a;
      double b = (double)imp_o[e];  si += b; si2 += b * b;
    }
    const double n  = (double)E_EXP;
    const double ml = sl / n, mi = si / n;
    const double varl = (sl2 - n * ml * ml) / (n - 1.0);
    const double vari = (si2 - n * mi * mi) / (n - 1.0);
    const double cvl = varl / (ml * ml + 1e-10);
    const double cvi = vari / (mi * mi + 1e-10);
    const double z  = (double)zsum[0] / (double)B_ROWS;
    out_lb[0] = (float)(cvi + cvl + z);
  }
}

// ---------- launch ----------

extern "C" void kernel_launch(void* const* d_in, const int* in_sizes, int n_in,
                              void* d_out, int out_size, void* d_ws, size_t ws_size,
                              hipStream_t stream) {
  const float* x   = (const float*)d_in[0];
  const float* wg  = (const float*)d_in[1];
  const float* wn  = (const float*)d_in[2];
  const float* eps = (const float*)d_in[3];

  float* out    = (float*)d_out;
  float* gates  = out;                                       // [B*E] (holds sdraw between k1,k2)
  float* load_o = out + (size_t)B_ROWS * E_EXP;              // [E]
  float* logits = load_o + E_EXP;                            // [B*E] (holds clean between k1,k2)
  float* lb     = logits + (size_t)B_ROWS * E_EXP;           // [1]
  float* imp    = lb + 1;                                    // [E]

  // workspace: zsum @0, flagcnt @8, flaglist @256, wt @256+4*FLAGCAP  (~384 KB total)
  float* zsum     = (float*)d_ws;
  int*   flagcnt  = (int*)d_ws + 2;
  int*   flaglist = (int*)((char*)d_ws + 256);
  f16*   wt       = (f16*)((char*)d_ws + 256 + 4 * FLAGCAP);

  init_acc<<<1, 128, 0, stream>>>(load_o, imp, zsum, flagcnt);
  prep_wt<<<512, 256, 0, stream>>>(wg, wn, wt);
  gemm_mfma<<<B_ROWS / 128, 256, 0, stream>>>(x, wt, logits, gates);
  epilogue_k<<<B_ROWS / 64, 256, 0, stream>>>(eps, gates, logits, load_o, imp, zsum, flagcnt, flaglist);
  fixup_k<<<512, 256, 0, stream>>>(x, wg, wn, eps, gates, logits, load_o, imp, zsum, flagcnt, flaglist);
  finalize_k<<<1, 64, 0, stream>>>(load_o, imp, zsum, lb);
}

// Round 5
// 271.292 us; speedup vs baseline: 55.9288x; 1.7938x over previous
//
#include <hip/hip_runtime.h>
#include <math.h>

#define B_ROWS 131072
#define D_DIM  1024
#define E_EXP  64
#define MARGIN 4e-3f

typedef _Float16 f16;
typedef _Float16 f16x8 __attribute__((ext_vector_type(8)));
typedef float    f32x4 __attribute__((ext_vector_type(4)));

#define AS1C(p) ((const __attribute__((address_space(1))) void*)(p))
#define AS3(p)  ((__attribute__((address_space(3))) void*)(p))

// ---------- helpers ----------

__device__ __forceinline__ float softplus_f(float t) {
  return (t > 20.0f) ? t : log1pf(expf(t));
}
__device__ __forceinline__ float ndtr_f(float z) {
  return 0.5f * erfcf(-z * 0.70710678118654752f);
}
__device__ __forceinline__ void argmax64(float& v, int& vi) {
  #pragma unroll
  for (int off = 32; off > 0; off >>= 1) {
    float ov = __shfl_xor(v, off, 64);
    int   oi = __shfl_xor(vi, off, 64);
    if (ov > v || (ov == v && oi < vi)) { v = ov; vi = oi; }
  }
}
__device__ __forceinline__ float sum64(float v) {
  #pragma unroll
  for (int off = 32; off > 0; off >>= 1) v += __shfl_xor(v, off, 64);
  return v;
}

// full-64-lane (lane==expert) row epilogue, used by fixup only
__device__ __forceinline__ void row_epilogue_exact(
    int row, int lane, float clean, float sd, float l,
    float* __restrict__ gates_buf, float* __restrict__ logits_buf,
    float& load_acc, float& imp_acc, float& z_acc)
{
  float v1 = l; int i1 = lane; argmax64(v1, i1);
  float v2 = (lane == i1) ? -INFINITY : l; int i2 = lane; argmax64(v2, i2);
  float v3 = (lane == i1 || lane == i2) ? -INFINITY : l; int i3 = lane; argmax64(v3, i3);
  (void)i3;
  const float e21 = expf(v2 - v1);
  const float g1  = 1.0f / (1.0f + e21);
  const float g2  = e21 * g1;
  const float gv  = (lane == i1) ? g1 : ((lane == i2) ? g2 : 0.0f);
  gates_buf [(size_t)row * E_EXP + lane] = gv;
  logits_buf[(size_t)row * E_EXP + lane] = l;
  const float ssum = sum64(expf(l - v1));
  z_acc += v1 + logf(ssum);
  const float thr = (l > v3) ? v3 : v2;
  load_acc += ndtr_f((clean - thr) / sd);
  imp_acc  += gv;
}

// ---------- kernels ----------

__global__ void init_acc(float* load_o, float* imp_o, float* zsum, int* flagcnt) {
  int t = threadIdx.x;
  if (t < 64) { load_o[t] = 0.0f; imp_o[t] = 0.0f; }
  if (t == 64) zsum[0] = 0.0f;
  if (t == 65) flagcnt[0] = 0;
}

// W^T f16 via coalesced LDS transpose. wt[col][k]; col 0..63 gate, 64..127 noise.
__global__ __launch_bounds__(256) void prep_wt(
    const float* __restrict__ wg, const float* __restrict__ wn, f16* __restrict__ wt) {
  __shared__ float tile[64][65];
  const int m  = blockIdx.x >> 4;       // 0 gate, 1 noise
  const int kt = blockIdx.x & 15;
  const int k0 = kt * 64;
  const float* src = m ? wn : wg;
  const int c = threadIdx.x & 63;
  const int r0 = threadIdx.x >> 6;
  #pragma unroll
  for (int r = r0; r < 64; r += 4)
    tile[r][c] = src[(size_t)(k0 + r) * 64 + c];   // coalesced read
  __syncthreads();
  const int j = threadIdx.x & 63;
  #pragma unroll
  for (int col = r0; col < 64; col += 4)
    wt[(size_t)(m * 64 + col) * 1024 + k0 + j] = (f16)tile[j][col];  // coalesced write
}

// Fused f16-MFMA GEMM + noisy-top-k epilogue.
// Block: 4 waves x 32 rows = 128 rows. Wave: 32 rows x 128 cols (64 gate + 64 noise).
__global__ __launch_bounds__(256, 3) void gemm_fused(
    const float* __restrict__ x, const f16* __restrict__ wt,
    const float* __restrict__ eps,
    float* __restrict__ gates_buf, float* __restrict__ logits_buf,
    float* __restrict__ load_o, float* __restrict__ imp_o, float* __restrict__ zsum,
    int* __restrict__ flagcnt, int* __restrict__ flaglist)
{
  __shared__ __align__(16) char wlds[2][16384];   // [buf][128 cols x 64 k x f16]

  const int tid  = threadIdx.x;
  const int lane = tid & 63;
  const int wid  = tid >> 6;
  const int l15  = lane & 15;
  const int l4   = lane >> 4;
  const size_t rowbase = (size_t)blockIdx.x * 128 + wid * 32;

  // ---- B staging via global_load_lds: linear LDS dest, pre-swizzled global src ----
  // piece i: dest byte = i*4096 + wid*1024 + lane*16  (wave-uniform base + lane*16)
  //   -> col = wid*8 + (lane>>3) + i*32, phys kbyte = (lane&7)*16
  //   logical k element = ((lane&7)*8) ^ ((lane>>3)<<3)   (involution swizzle)
  const int scol0 = wid * 8 + (lane >> 3);
  const int skel  = ((lane & 7) * 8) ^ ((lane >> 3) << 3);
  const f16* wsrc0 = wt + (size_t)(scol0 +  0) * 1024 + skel;
  const f16* wsrc1 = wt + (size_t)(scol0 + 32) * 1024 + skel;
  const f16* wsrc2 = wt + (size_t)(scol0 + 64) * 1024 + skel;
  const f16* wsrc3 = wt + (size_t)(scol0 + 96) * 1024 + skel;

#define ISSUE_B(buf, kc) do {                                                                      \
    __builtin_amdgcn_global_load_lds(AS1C(wsrc0 + (kc) * 64), AS3(&wlds[buf][0*4096 + wid*1024]), 16, 0, 0); \
    __builtin_amdgcn_global_load_lds(AS1C(wsrc1 + (kc) * 64), AS3(&wlds[buf][1*4096 + wid*1024]), 16, 0, 0); \
    __builtin_amdgcn_global_load_lds(AS1C(wsrc2 + (kc) * 64), AS3(&wlds[buf][2*4096 + wid*1024]), 16, 0, 0); \
    __builtin_amdgcn_global_load_lds(AS1C(wsrc3 + (kc) * 64), AS3(&wlds[buf][3*4096 + wid*1024]), 16, 0, 0); \
  } while (0)

  // ---- A pointers: lane covers rows (rowbase + rt*16 + l15), k = l4*8.. ----
  const float* xp0 = x + (rowbase +  0 + l15) * D_DIM + l4 * 8;
  const float* xp1 = x + (rowbase + 16 + l15) * D_DIM + l4 * 8;

  f32x4 acc[2][8];
  #pragma unroll
  for (int rt = 0; rt < 2; ++rt)
    #pragma unroll
    for (int et = 0; et < 8; ++et) acc[rt][et] = (f32x4)0.0f;

  // xa[kl*4 + rt*2 + h]
  float4 xa[8];
#define LOAD_A(kc) do {                                                  \
    _Pragma("unroll")                                                    \
    for (int kl = 0; kl < 2; ++kl) {                                     \
      xa[kl*4 + 0] = *(const float4*)(xp0 + (kc)*64 + kl*32 + 0);        \
      xa[kl*4 + 1] = *(const float4*)(xp0 + (kc)*64 + kl*32 + 4);        \
      xa[kl*4 + 2] = *(const float4*)(xp1 + (kc)*64 + kl*32 + 0);        \
      xa[kl*4 + 3] = *(const float4*)(xp1 + (kc)*64 + kl*32 + 4);        \
    }                                                                    \
  } while (0)

  // prologue
  ISSUE_B(0, 0);
  LOAD_A(0);
  __syncthreads();

  #pragma unroll 1
  for (int kc = 0; kc < 16; ++kc) {
    const int buf = kc & 1;

    // convert A(kc) -> f16 frags (consumes xa; compiler waits on the loads)
    f16x8 af[2][2];   // [kl][rt]
    #pragma unroll
    for (int kl = 0; kl < 2; ++kl)
      #pragma unroll
      for (int rt = 0; rt < 2; ++rt) {
        #pragma unroll
        for (int h = 0; h < 2; ++h) {
          const float4 v = xa[kl*4 + rt*2 + h];
          af[kl][rt][h*4 + 0] = (f16)v.x;
          af[kl][rt][h*4 + 1] = (f16)v.y;
          af[kl][rt][h*4 + 2] = (f16)v.z;
          af[kl][rt][h*4 + 3] = (f16)v.w;
        }
      }

    // prefetch next chunk (async B -> LDS[buf^1], A -> regs)
    if (kc < 15) {
      ISSUE_B(buf ^ 1, kc + 1);
      LOAD_A(kc + 1);
    }

    // MFMA: 2 kl x 8 et x 2 rt
    #pragma unroll
    for (int kl = 0; kl < 2; ++kl) {
      #pragma unroll
      for (int et = 0; et < 8; ++et) {
        const int bcol = et * 16 + l15;
        const int boff = (bcol * 128 + kl * 64 + l4 * 16) ^ ((l15 & 7) << 4);
        const f16x8 b = *(const f16x8*)(&wlds[buf][boff]);
        acc[0][et] = __builtin_amdgcn_mfma_f32_16x16x32_f16(af[kl][0], b, acc[0][et], 0, 0, 0);
        acc[1][et] = __builtin_amdgcn_mfma_f32_16x16x32_f16(af[kl][1], b, acc[1][et], 0, 0, 0);
      }
    }

    __syncthreads();   // drains prefetch (vmcnt) + publishes LDS[buf^1]
  }
#undef ISSUE_B
#undef LOAD_A

  // ---- fused epilogue: acc[rt][0..3] = clean, acc[rt][4..7] = sdraw ----
  float load_acc[4] = {0.f, 0.f, 0.f, 0.f};
  float imp_acc[4]  = {0.f, 0.f, 0.f, 0.f};
  float z_acc = 0.f;

  #pragma unroll
  for (int rt = 0; rt < 2; ++rt) {
    #pragma unroll
    for (int rg = 0; rg < 4; ++rg) {
      const size_t row = rowbase + rt * 16 + l4 * 4 + rg;
      float cl[4], sd[4], lg[4];
      #pragma unroll
      for (int j = 0; j < 4; ++j) {
        cl[j] = acc[rt][j][rg];
        sd[j] = softplus_f(acc[rt][4 + j][rg]) + 0.01f;
        const float ev = eps[row * E_EXP + j * 16 + l15];
        lg[j] = fmaf(ev, sd[j], cl[j]);
      }
      // top-1 over the row (16 lanes x 4 local)
      float v = lg[0]; int c = l15;
      #pragma unroll
      for (int j = 1; j < 4; ++j) {
        const int cj = j * 16 + l15;
        if (lg[j] > v || (lg[j] == v && cj < c)) { v = lg[j]; c = cj; }
      }
      #pragma unroll
      for (int off = 1; off < 16; off <<= 1) {
        const float ov = __shfl_xor(v, off, 64);
        const int   oc = __shfl_xor(c, off, 64);
        if (ov > v || (ov == v && oc < c)) { v = ov; c = oc; }
      }
      const float v1 = v; const int i1 = c;
      // top-2
      v = -INFINITY; c = 1 << 30;
      #pragma unroll
      for (int j = 0; j < 4; ++j) {
        const int cj = j * 16 + l15;
        if (cj != i1 && (lg[j] > v || (lg[j] == v && cj < c))) { v = lg[j]; c = cj; }
      }
      #pragma unroll
      for (int off = 1; off < 16; off <<= 1) {
        const float ov = __shfl_xor(v, off, 64);
        const int   oc = __shfl_xor(c, off, 64);
        if (ov > v || (ov == v && oc < c)) { v = ov; c = oc; }
      }
      const float v2 = v; const int i2 = c;
      // top-3 (value only)
      float v3 = -INFINITY;
      #pragma unroll
      for (int j = 0; j < 4; ++j) {
        const int cj = j * 16 + l15;
        if (cj != i1 && cj != i2) v3 = fmaxf(v3, lg[j]);
      }
      #pragma unroll
      for (int off = 1; off < 16; off <<= 1) v3 = fmaxf(v3, __shfl_xor(v3, off, 64));

      if (v2 - v3 >= MARGIN) {
        const float e21 = expf(v2 - v1);
        const float g1  = 1.0f / (1.0f + e21);
        const float g2  = e21 * g1;
        float s = 0.f;
        #pragma unroll
        for (int j = 0; j < 4; ++j) s += expf(lg[j] - v1);
        #pragma unroll
        for (int off = 1; off < 16; off <<= 1) s += __shfl_xor(s, off, 64);
        if (l15 == 0) z_acc += v1 + logf(s);
        #pragma unroll
        for (int j = 0; j < 4; ++j) {
          const int cj = j * 16 + l15;
          const float gv = (cj == i1) ? g1 : ((cj == i2) ? g2 : 0.0f);
          gates_buf [row * E_EXP + cj] = gv;
          logits_buf[row * E_EXP + cj] = lg[j];
          imp_acc[j] += gv;
          const float thr = (lg[j] > v3) ? v3 : v2;
          load_acc[j] += ndtr_f((cl[j] - thr) / sd[j]);
        }
      } else {
        if (l15 == 0) { const int idx = atomicAdd(flagcnt, 1); flaglist[idx] = (int)row; }
      }
    }
  }

  // ---- block-level reduction of load/imp/z, then one atomic set per block ----
  float* red = (float*)&wlds[0][0];   // [0..255] load, [256..511] imp, [512..515] z
  #pragma unroll
  for (int j = 0; j < 4; ++j) {
    float L = load_acc[j]; L += __shfl_xor(L, 16, 64); L += __shfl_xor(L, 32, 64);
    float I = imp_acc[j];  I += __shfl_xor(I, 16, 64); I += __shfl_xor(I, 32, 64);
    if (l4 == 0) {
      red[wid * 64 + j * 16 + l15]       = L;
      red[256 + wid * 64 + j * 16 + l15] = I;
    }
  }
  {
    const float zw = sum64(z_acc);
    if (lane == 0) red[512 + wid] = zw;
  }
  __syncthreads();
  if (wid == 0) {
    const float L = red[lane] + red[64 + lane] + red[128 + lane] + red[192 + lane];
    const float I = red[256 + lane] + red[320 + lane] + red[384 + lane] + red[448 + lane];
    atomicAdd(&load_o[lane], L);
    atomicAdd(&imp_o[lane],  I);
    if (lane == 0) atomicAdd(zsum, red[512] + red[513] + red[514] + red[515]);
  }
}

// exact fp32 recompute of flagged rows, 4 rows per w-pass
__global__ __launch_bounds__(256) void fixup_k(
    const float* __restrict__ x, const float* __restrict__ wg, const float* __restrict__ wn,
    const float* __restrict__ eps,
    float* __restrict__ gates_buf, float* __restrict__ logits_buf,
    float* __restrict__ load_o, float* __restrict__ imp_o, float* __restrict__ zsum,
    const int* __restrict__ flagcnt, const int* __restrict__ flaglist)
{
  const int lane = threadIdx.x & 63;
  const int wid  = threadIdx.x >> 6;
  __shared__ float redg[4][4][64], redn[4][4][64];

  const int nf = *flagcnt;

  for (int it = blockIdx.x * 4; it < nf; it += gridDim.x * 4) {
    const int nr = (nf - it < 4) ? (nf - it) : 4;
    int rows[4];
    #pragma unroll
    for (int rr = 0; rr < 4; ++rr) rows[rr] = flaglist[it + ((rr < nr) ? rr : 0)];

    float dg[4] = {0.f,0.f,0.f,0.f}, dn[4] = {0.f,0.f,0.f,0.f};
    const int dbase = wid * 256;
    for (int d = 0; d < 256; d += 4) {
      const int db = (dbase + d) * E_EXP + lane;
      const float wgv0 = wg[db], wgv1 = wg[db + 64], wgv2 = wg[db + 128], wgv3 = wg[db + 192];
      const float wnv0 = wn[db], wnv1 = wn[db + 64], wnv2 = wn[db + 128], wnv3 = wn[db + 192];
      #pragma unroll
      for (int rr = 0; rr < 4; ++rr) {
        const float4 xv = *(const float4*)(x + (size_t)rows[rr] * D_DIM + dbase + d);
        dg[rr] = fmaf(xv.x, wgv0, dg[rr]);  dn[rr] = fmaf(xv.x, wnv0, dn[rr]);
        dg[rr] = fmaf(xv.y, wgv1, dg[rr]);  dn[rr] = fmaf(xv.y, wnv1, dn[rr]);
        dg[rr] = fmaf(xv.z, wgv2, dg[rr]);  dn[rr] = fmaf(xv.z, wnv2, dn[rr]);
        dg[rr] = fmaf(xv.w, wgv3, dg[rr]);  dn[rr] = fmaf(xv.w, wnv3, dn[rr]);
      }
    }
    #pragma unroll
    for (int rr = 0; rr < 4; ++rr) { redg[wid][rr][lane] = dg[rr]; redn[wid][rr][lane] = dn[rr]; }
    __syncthreads();
    if (wid < nr) {
      const int row = rows[wid];
      const float clean = redg[0][wid][lane] + redg[1][wid][lane] + redg[2][wid][lane] + redg[3][wid][lane];
      const float sdraw = redn[0][wid][lane] + redn[1][wid][lane] + redn[2][wid][lane] + redn[3][wid][lane];
      const float sd = softplus_f(sdraw) + 0.01f;
      const float ev = eps[(size_t)row * E_EXP + lane];
      const float l  = fmaf(ev, sd, clean);
      float la = 0.f, ia = 0.f, za = 0.f;
      row_epilogue_exact(row, lane, clean, sd, l, gates_buf, logits_buf, la, ia, za);
      atomicAdd(&load_o[lane], la);
      atomicAdd(&imp_o[lane],  ia);
      if (lane == 0) atomicAdd(zsum, za);
    }
    __syncthreads();
  }
}

__global__ void finalize_k(const float* __restrict__ load_o,
                           const float* __restrict__ imp_o,
                           const float* __restrict__ zsum,
                           float* __restrict__ out_lb) {
  if (threadIdx.x == 0 && blockIdx.x == 0) {
    double sl = 0.0, sl2 = 0.0, si = 0.0, si2 = 0.0;
    for (int e = 0; e < E_EXP; ++e) {
      double a = (double)load_o[e]; sl += a; sl2 += a * a;
      double b = (double)imp_o[e];  si += b; si2 += b * b;
    }
    const double n  = (double)E_EXP;
    const double ml = sl / n, mi = si / n;
    const double varl = (sl2 - n * ml * ml) / (n - 1.0);
    const double vari = (si2 - n * mi * mi) / (n - 1.0);
    const double cvl = varl / (ml * ml + 1e-10);
    const double cvi = vari / (mi * mi + 1e-10);
    const double z  = (double)zsum[0] / (double)B_ROWS;
    out_lb[0] = (float)(cvi + cvl + z);
  }
}

// ---------- launch ----------

extern "C" void kernel_launch(void* const* d_in, const int* in_sizes, int n_in,
                              void* d_out, int out_size, void* d_ws, size_t ws_size,
                              hipStream_t stream) {
  const float* x   = (const float*)d_in[0];
  const float* wg  = (const float*)d_in[1];
  const float* wn  = (const float*)d_in[2];
  const float* eps = (const float*)d_in[3];

  float* out    = (float*)d_out;
  float* gates  = out;                                       // [B*E]
  float* load_o = out + (size_t)B_ROWS * E_EXP;              // [E]
  float* logits = load_o + E_EXP;                            // [B*E]
  float* lb     = logits + (size_t)B_ROWS * E_EXP;           // [1]
  float* imp    = lb + 1;                                    // [E]

  // workspace: zsum @0, flagcnt @8, flaglist @256 (512KB), wt after
  float* zsum     = (float*)d_ws;
  int*   flagcnt  = (int*)d_ws + 2;
  int*   flaglist = (int*)((char*)d_ws + 256);
  f16*   wt       = (f16*)((char*)d_ws + 256 + 4 * (size_t)B_ROWS);

  init_acc<<<1, 128, 0, stream>>>(load_o, imp, zsum, flagcnt);
  prep_wt<<<32, 256, 0, stream>>>(wg, wn, wt);
  gemm_fused<<<B_ROWS / 128, 256, 0, stream>>>(
      x, wt, eps, gates, logits, load_o, imp, zsum, flagcnt, flaglist);
  fixup_k<<<512, 256, 0, stream>>>(x, wg, wn, eps, gates, logits, load_o, imp, zsum, flagcnt, flaglist);
  finalize_k<<<1, 64, 0, stream>>>(load_o, imp, zsum, lb);
}